// Round 8
// baseline (407.636 us; speedup 1.0000x reference)
//
#include <hip/hip_runtime.h>
#include <stdint.h>

#define NBOX 25200
#define NCH  16
#define TOPK 1024
#define NTH  1024
#define NBUCK 4096
#define CAP  2048        // scatter capacity (expected M ~ 1027)
#define K1_SLICES 16
#define K1_TH 256
#define ROWS_PER_SLICE (NBOX / K1_SLICES)   // 1575
#define K1_ITERS 7                          // ceil(1575/256)
#define SEGCAP 1600      // >= ROWS_PER_SLICE: per-slice segment can never overflow

// exact threshold: RN_f32(inter/den) > 0.45f  <=>  (double)inter > M45*(double)den
// (0.45f = 0x3EE66666, even mantissa -> midpoint ties round down; 25b x 24b exact in f64)
#define M45 ((double)0.45f + 0x1p-26)

// ws layout (no zero-init required: counts/done always written before read)
#define OFF_KEYS  4096                                        // cnts: 64*16 u32 = 4096 B
#define OFF_BOXES (OFF_KEYS + 64 * K1_SLICES * SEGCAP * 8)    // 13111296, 16B aligned
#define OFF_MASKS (OFF_BOXES + 64 * TOPK * 16)                // 14159872, 8B aligned
#define OFF_DONE  (OFF_MASKS + 64 * 16 * TOPK * 8)            // 22548480, 64 u32

__device__ __forceinline__ unsigned long long make_key(float p, uint32_t r) {
  return ((unsigned long long)__float_as_uint(p) << 32) |
         (unsigned long long)(0xFFFFFFFFu - r);
}

__device__ __forceinline__ uint32_t bucket_of(uint32_t bits) {
  uint32_t bk = (bits - 0x3E800001u) >> 12;
  return bk > (NBUCK - 1u) ? (NBUCK - 1u) : bk;
}

// ---------------- K1: score scan + deterministic segment append (full-GPU, no atomics) ----
__global__ __launch_bounds__(K1_TH) void score_kernel(const float* __restrict__ x,
                                                      unsigned long long* __restrict__ keys,
                                                      uint32_t* __restrict__ cnts) {
  const int img = blockIdx.x >> 4;
  const int slice = blockIdx.x & (K1_SLICES - 1);
  const int t = threadIdx.x;
  const int lane = t & 63;
  const int wid = t >> 6;                              // 4 waves per block
  const float* __restrict__ xb = x + (size_t)img * NBOX * NCH;
  unsigned long long* __restrict__ kl = keys + ((size_t)img * K1_SLICES + slice) * SEGCAP;
  const int row0 = slice * ROWS_PER_SLICE;

  float p[K1_ITERS];
  uint32_t mask = 0;
#pragma unroll
  for (int j = 0; j < K1_ITERS - 1; ++j) {             // 6 full iterations
    const size_t ro = (size_t)(row0 + t + j * K1_TH) * NCH;
    const float v = xb[ro + 4] * xb[ro + 15];          // exact ref arithmetic
    if (v > 0.25f) mask |= (1u << j);
    p[j] = v;
  }
  {                                                    // tail (rows 1536..1574)
    const int rr = t + (K1_ITERS - 1) * K1_TH;
    float v = 0.0f;
    if (rr < ROWS_PER_SLICE) {
      const size_t ro = (size_t)(row0 + rr) * NCH;
      v = xb[ro + 4] * xb[ro + 15];
      if (v > 0.25f) mask |= (1u << (K1_ITERS - 1));
    }
    p[K1_ITERS - 1] = v;
  }

  // wave-inclusive prefix of per-lane counts
  const int cntl = __popc(mask);
  uint32_t inc = (uint32_t)cntl;
#pragma unroll
  for (int off = 1; off < 64; off <<= 1) {
    const uint32_t o = __shfl_up(inc, off);
    if (lane >= off) inc += o;
  }
  const uint32_t wtotal = __shfl(inc, 63);

  __shared__ uint32_t s_wtot[4];
  if (lane == 63) s_wtot[wid] = wtotal;
  __syncthreads();
  uint32_t base = 0;
#pragma unroll
  for (int w = 0; w < 4; ++w) if (w < wid) base += s_wtot[w];

  uint32_t pos = base + (inc - (uint32_t)cntl);        // <= 1575 < SEGCAP: no bound check
#pragma unroll
  for (int j = 0; j < K1_ITERS; ++j) {
    if ((mask >> j) & 1u) {
      kl[pos] = make_key(p[j], (uint32_t)(row0 + t + j * K1_TH));
      ++pos;
    }
  }
  if (t == K1_TH - 1)                                  // wid==3, lane==63
    cnts[img * K1_SLICES + slice] = base + wtotal;
}

// ---------------- K2: select + bucket-scatter sort + gather (one block/image) ----------------
__global__ __launch_bounds__(NTH, 1) void select_kernel(const float* __restrict__ x,
                                                        const unsigned long long* __restrict__ keys,
                                                        const uint32_t* __restrict__ cnts,
                                                        float* __restrict__ out,
                                                        float4* __restrict__ boxes,
                                                        uint32_t* __restrict__ done) {
  __shared__ uint32_t s_hist[NBUCK];                 // 16 KB (pristine counts)
  __shared__ uint32_t s_pos[NBUCK];                  // 16 KB (scatter cursors)
  __shared__ unsigned long long s_sorted[CAP];       // 16 KB
  __shared__ unsigned long long s_final[TOPK];       // 8 KB
  __shared__ uint32_t s_wsum[16];
  __shared__ uint32_t s_cnt16[K1_SLICES];
  __shared__ int s_cut;

  const int t = threadIdx.x;
  const int b = blockIdx.x;
  const int lane = t & 63;
  const int wid = t >> 6;
  const float* __restrict__ xb = x + (size_t)b * NBOX * NCH;
  const unsigned long long* __restrict__ kb0 = keys + (size_t)b * K1_SLICES * SEGCAP;

  // ---- init + histogram over 16 segments
#pragma unroll
  for (int j = 0; j < NBUCK / NTH; ++j) s_hist[t + j * NTH] = 0u;
  s_final[t] = 0ull;
  if (t < K1_SLICES) {
    uint32_t c = cnts[b * K1_SLICES + t];
    s_cnt16[t] = (c > SEGCAP) ? SEGCAP : c;          // defensive clamp
  }
  if (t == 0) { s_cut = 0; done[b] = 0u; }           // arm mask/greedy arrival counter
  __syncthreads();
#pragma unroll
  for (int s = 0; s < K1_SLICES; ++s) {
    const int cs_ = (int)s_cnt16[s];
    const unsigned long long* seg = kb0 + (size_t)s * SEGCAP;
    for (int j = t; j < cs_; j += NTH)
      atomicAdd(&s_hist[bucket_of((uint32_t)(seg[j] >> 32))], 1u);
  }
  __syncthreads();

  // ---- fine suffix scan over 4096 buckets (thread t owns quad 4t..4t+3)
  const uint32_t h0 = s_hist[4 * t], h1 = s_hist[4 * t + 1];
  const uint32_t h2 = s_hist[4 * t + 2], h3 = s_hist[4 * t + 3];
  const uint32_t qs = h0 + h1 + h2 + h3;
  uint32_t v = qs;
#pragma unroll
  for (int off = 1; off < 64; off <<= 1) {           // inclusive suffix within wave
    const uint32_t o = __shfl_down(v, off);
    if (lane + off < 64) v += o;
  }
  if (lane == 0) s_wsum[wid] = v;
  __syncthreads();
  uint32_t tail = 0;
#pragma unroll
  for (int w = 0; w < 16; ++w) if (w > wid) tail += s_wsum[w];
  const uint32_t after = (v - qs) + tail;            // sum of buckets after my quad
  const uint32_t e3 = after, e2 = after + h3, e1 = e2 + h2, e0 = e1 + h1;
  s_pos[4 * t] = e0; s_pos[4 * t + 1] = e1;
  s_pos[4 * t + 2] = e2; s_pos[4 * t + 3] = e3;
  int cand = -1;                                     // cutoff vote: wave-reduced max
  if (e3 + h3 >= TOPK) cand = 4 * t + 3;
  else if (e2 + h2 >= TOPK) cand = 4 * t + 2;
  else if (e1 + h1 >= TOPK) cand = 4 * t + 1;
  else if (e0 + h0 >= TOPK) cand = 4 * t;
  int wmax = cand;
#pragma unroll
  for (int off = 32; off > 0; off >>= 1) {
    const int o = __shfl_down(wmax, off);
    if (o > wmax) wmax = o;
  }
  if (lane == 0 && wmax >= 0) atomicMax(&s_cut, wmax);
  __syncthreads();
  const int cut = s_cut;
  int M = (int)(s_pos[cut] + s_hist[cut]);           // # keys in buckets >= cut
  if (M > CAP) M = CAP;
  __syncthreads();                                   // all read M before cursors move

  // ---- scatter keys >= cut into bucket slices
#pragma unroll
  for (int s = 0; s < K1_SLICES; ++s) {
    const int cs_ = (int)s_cnt16[s];
    const unsigned long long* seg = kb0 + (size_t)s * SEGCAP;
    for (int j = t; j < cs_; j += NTH) {
      const unsigned long long key = seg[j];
      const uint32_t bk = bucket_of((uint32_t)(key >> 32));
      if ((int)bk >= cut) {
        const uint32_t pos = atomicAdd(&s_pos[bk], 1u);
        if (pos < CAP) s_sorted[pos] = key;
      }
    }
  }
  __syncthreads();

  // ---- exact in-bucket rank (slices are tiny: ~1-3 keys)
  for (int p = t; p < M; p += NTH) {
    const unsigned long long key = s_sorted[p];
    const uint32_t bk = bucket_of((uint32_t)(key >> 32));
    int end = (int)s_pos[bk]; if (end > M) end = M;
    int start = end - (int)s_hist[bk]; if (start < 0) start = 0;
    int lr = 0;
    for (int q = start; q < end; ++q) lr += (int)(s_sorted[q] > key);
    const int fp = start + lr;
    if (fp < TOPK) s_final[fp] = key;
  }
  __syncthreads();

  // ---- gather rows of top-1024; write unscaled dets + boxes
  const unsigned long long mykey = s_final[t];
  const uint32_t sbits = (uint32_t)(mykey >> 32);
  const int src = (int)(0xFFFFFFFFu - (uint32_t)(mykey & 0xFFFFFFFFull));
  const bool valid = (sbits != 0u);
  const float conf = valid ? __uint_as_float(sbits) : 0.0f;

  float x1 = 0.f, y1 = 0.f, x2 = 0.f, y2 = 0.f;
  float lm0=0.f,lm1=0.f,lm2=0.f,lm3=0.f,lm4=0.f,lm5=0.f,lm6=0.f,lm7=0.f,lm8=0.f,lm9=0.f;
  if (valid) {
    const float4* rp = (const float4*)(xb + (size_t)src * NCH);
    const float4 q0 = rp[0], q1 = rp[1], q2 = rp[2], q3 = rp[3];
    x1 = q0.x - q0.z * 0.5f;
    y1 = q0.y - q0.w * 0.5f;
    x2 = q0.x + q0.z * 0.5f;
    y2 = q0.y + q0.w * 0.5f;
    lm0 = q1.y; lm1 = q1.z; lm2 = q1.w;
    lm3 = q2.x; lm4 = q2.y; lm5 = q2.z; lm6 = q2.w;
    lm7 = q3.x; lm8 = q3.y; lm9 = q3.z;
  }
  boxes[(size_t)b * TOPK + t] = make_float4(x1, y1, x2, y2);
  float4* op = (float4*)(out + ((size_t)b * TOPK + (size_t)t) * NCH);
  op[0] = make_float4(x1, y1, x2, y2);
  op[1] = make_float4(conf, lm0, lm1, lm2);
  op[2] = make_float4(lm3, lm4, lm5, lm6);
  op[3] = make_float4(lm7, lm8, lm9, 0.0f);
}

// ---------------- K3: mask + fused greedy (last block of each image runs closure) ----------
// grid = 64 images x 40 slots; block = 256 thr; wave w computes word jw = wg*4+w of rowtile rt.
__global__ __launch_bounds__(256) void mask_greedy_kernel(const float4* __restrict__ boxes,
                                                          unsigned long long* __restrict__ masks,
                                                          uint32_t* __restrict__ done,
                                                          float* __restrict__ out) {
  const int img = blockIdx.x / 40;
  const int s = blockIdx.x % 40;
  int rt, wg;
  if (s < 4)        { rt = s;                wg = 0; }
  else if (s < 12)  { rt = 4 + ((s - 4) >> 1);  wg = (s - 4) & 1; }
  else if (s < 24)  { rt = 8 + (s - 12) / 3;    wg = (s - 12) % 3; }
  else              { rt = 12 + ((s - 24) >> 2); wg = (s - 24) & 3; }

  const int t = threadIdx.x;
  const int lane = t & 63;
  const int wid = t >> 6;
  const int jw = wg * 4 + wid;

  __shared__ float4 s_rbox[64];
  __shared__ float s_rarea[64];
  __shared__ uint32_t s_arriv;
  if (t < 64) {
    const float4 rb = boxes[(size_t)img * TOPK + rt * 64 + t];
    s_rbox[t] = rb;
    s_rarea[t] = fmaxf(rb.z - rb.x, 0.f) * fmaxf(rb.w - rb.y, 0.f);
  }
  __syncthreads();

  if (jw <= rt) {                                     // waves above diagonal skip compute
    const float4 cb = boxes[(size_t)img * TOPK + jw * 64 + lane];  // my column box
    const float ca = fmaxf(cb.z - cb.x, 0.f) * fmaxf(cb.w - cb.y, 0.f);
    unsigned long long myword = 0ull;
    for (int rl = 0; rl < 64; ++rl) {
      const float4 rb = s_rbox[rl];                   // broadcast row box
      const float ra = s_rarea[rl];                   // hoisted row area
      const float iw = fmaxf(fminf(cb.z, rb.z) - fmaxf(cb.x, rb.x), 0.f);
      const float ih = fmaxf(fminf(cb.w, rb.w) - fmaxf(cb.y, rb.y), 0.f);
      const float inter = iw * ih;
      const float den = ((ca + ra) - inter) + 1e-9f;  // area_col + area_row, ref order
      const bool sup = (double)inter > M45 * (double)den;
      unsigned long long bal = __ballot(sup);
      if (jw == rt) bal &= ((1ull << rl) - 1ull);     // only cols < row on the diagonal
      if (lane == rl) myword = bal;
    }
    masks[((size_t)img * 16 + jw) * TOPK + rt * 64 + lane] = myword;
  }

  // ---- arrival: last of the image's 40 blocks runs the greedy closure inline
  __threadfence();                                    // release my mask stores (device scope)
  __syncthreads();                                    // whole block's stores fenced
  if (t == 0) s_arriv = atomicAdd(&done[img], 1u);    // device-scope arrival tick
  __syncthreads();
  if (s_arriv != 39u) return;                         // not last: done
  __threadfence();                                    // acquire: see all 40 blocks' masks

  // greedy closure, 256 threads, 4 rows/thread: row r_k = k*256+t lies in tile 4k+wid,
  // so wave (T&3) holds exactly rows T*64+lane of tile T at k = T>>2.
  const unsigned long long* __restrict__ mb = masks + (size_t)img * 16 * TOPK;
  __shared__ unsigned long long s_alive[16];
  unsigned long long diag[4], acc4[4];
  bool keep4[4];
#pragma unroll
  for (int k = 0; k < 4; ++k) {
    const int tile = 4 * k + wid;
    diag[k] = mb[(size_t)tile * TOPK + (k * 256 + t)];   // own-tile word (lower-masked)
    acc4[k] = 0ull;
    keep4[k] = true;
  }

  for (int T = 0; T < 16; ++T) {
    // preload cross-tile words for my rows in later tiles (independent of s_alive)
    unsigned long long mw[4];
#pragma unroll
    for (int k = 0; k < 4; ++k)
      mw[k] = (4 * k + wid > T) ? mb[(size_t)T * TOPK + (k * 256 + t)] : 0ull;

    if ((T & 3) == wid) {                             // this wave resolves tile T's diagonal
      const int k = T >> 2;
      bool kp = keep4[k];
      if (acc4[k]) kp = false;                        // killed by earlier (finalized) tiles
      const unsigned long long dg = diag[k];
      unsigned long long vm = __ballot(dg != 0ull);   // victim-sparse chain
      while (vm) {
        const int vv = __ffsll((long long)vm) - 1;
        vm &= vm - 1ull;
        const unsigned long long alive = __ballot(kp);
        if (lane == vv && (alive & dg)) kp = false;
      }
      keep4[k] = kp;
      const unsigned long long fin = __ballot(kp);
      if (lane == 0) s_alive[T] = fin;
    }
    __syncthreads();
    const unsigned long long am = s_alive[T];
#pragma unroll
    for (int k = 0; k < 4; ++k)
      if (4 * k + wid > T) acc4[k] |= mw[k] & am;
  }

#pragma unroll
  for (int k = 0; k < 4; ++k) {
    if (!keep4[k]) {
      float4* op = (float4*)(out + ((size_t)img * TOPK + (size_t)(k * 256 + t)) * NCH);
      const float4 z = make_float4(0.f, 0.f, 0.f, 0.f);
      op[0] = z; op[1] = z; op[2] = z; op[3] = z;
    }
  }
}

extern "C" void kernel_launch(void* const* d_in, const int* in_sizes, int n_in,
                              void* d_out, int out_size, void* d_ws, size_t ws_size,
                              hipStream_t stream) {
  const float* x = (const float*)d_in[0];
  float* out = (float*)d_out;
  uint32_t* cnts = (uint32_t*)d_ws;                                   // 64*16 u32, always written
  unsigned long long* keys = (unsigned long long*)((char*)d_ws + OFF_KEYS);
  float4* boxes = (float4*)((char*)d_ws + OFF_BOXES);
  unsigned long long* masks = (unsigned long long*)((char*)d_ws + OFF_MASKS);
  uint32_t* done = (uint32_t*)((char*)d_ws + OFF_DONE);               // zeroed by select

  score_kernel<<<dim3(64 * K1_SLICES), dim3(K1_TH), 0, stream>>>(x, keys, cnts);
  select_kernel<<<dim3(64), dim3(NTH), 0, stream>>>(x, keys, cnts, out, boxes, done);
  mask_greedy_kernel<<<dim3(64 * 40), dim3(256), 0, stream>>>(boxes, masks, done, out);
}

// Round 9
// 207.415 us; speedup vs baseline: 1.9653x; 1.9653x over previous
//
#include <hip/hip_runtime.h>
#include <stdint.h>

#define NBOX 25200
#define NCH  16
#define TOPK 1024
#define NTH  1024
#define NBUCK 4096
#define CAP  2048        // scatter capacity (expected M ~ 1027)
#define K1_SLICES 16
#define K1_TH 256
#define ROWS_PER_SLICE (NBOX / K1_SLICES)   // 1575
#define K1_ITERS 7                          // ceil(1575/256)
#define SEGCAP 1600      // >= ROWS_PER_SLICE: per-slice segment can never overflow
#define MASK_BLKS 34     // ceil(136 word-tiles / 4 waves): perfect triangular packing

// exact threshold: RN_f32(inter/den) > 0.45f  <=>  (double)inter > M45*(double)den
// (0.45f = 0x3EE66666, even mantissa -> midpoint ties round down; 25b x 24b exact in f64)
#define M45 ((double)0.45f + 0x1p-26)

// ws layout (no zero-init required: counts always written before read)
#define OFF_KEYS  4096                                        // cnts: 64*16 u32 = 4096 B
#define OFF_BOXES (OFF_KEYS + 64 * K1_SLICES * SEGCAP * 8)    // 16B aligned
#define OFF_MASKS (OFF_BOXES + 64 * TOPK * 16)                // 8B aligned

__device__ __forceinline__ unsigned long long make_key(float p, uint32_t r) {
  return ((unsigned long long)__float_as_uint(p) << 32) |
         (unsigned long long)(0xFFFFFFFFu - r);
}

__device__ __forceinline__ uint32_t bucket_of(uint32_t bits) {
  uint32_t bk = (bits - 0x3E800001u) >> 12;
  return bk > (NBUCK - 1u) ? (NBUCK - 1u) : bk;
}

// ---------------- K1: score scan + deterministic segment append (full-GPU, no atomics) ----
__global__ __launch_bounds__(K1_TH) void score_kernel(const float* __restrict__ x,
                                                      unsigned long long* __restrict__ keys,
                                                      uint32_t* __restrict__ cnts) {
  const int img = blockIdx.x >> 4;
  const int slice = blockIdx.x & (K1_SLICES - 1);
  const int t = threadIdx.x;
  const int lane = t & 63;
  const int wid = t >> 6;                              // 4 waves per block
  const float* __restrict__ xb = x + (size_t)img * NBOX * NCH;
  unsigned long long* __restrict__ kl = keys + ((size_t)img * K1_SLICES + slice) * SEGCAP;
  const int row0 = slice * ROWS_PER_SLICE;

  float p[K1_ITERS];
  uint32_t mask = 0;
#pragma unroll
  for (int j = 0; j < K1_ITERS - 1; ++j) {             // 6 full iterations
    const size_t ro = (size_t)(row0 + t + j * K1_TH) * NCH;
    const float v = xb[ro + 4] * xb[ro + 15];          // exact ref arithmetic
    if (v > 0.25f) mask |= (1u << j);
    p[j] = v;
  }
  {                                                    // tail (rows 1536..1574)
    const int rr = t + (K1_ITERS - 1) * K1_TH;
    float v = 0.0f;
    if (rr < ROWS_PER_SLICE) {
      const size_t ro = (size_t)(row0 + rr) * NCH;
      v = xb[ro + 4] * xb[ro + 15];
      if (v > 0.25f) mask |= (1u << (K1_ITERS - 1));
    }
    p[K1_ITERS - 1] = v;
  }

  // wave-inclusive prefix of per-lane counts
  const int cntl = __popc(mask);
  uint32_t inc = (uint32_t)cntl;
#pragma unroll
  for (int off = 1; off < 64; off <<= 1) {
    const uint32_t o = __shfl_up(inc, off);
    if (lane >= off) inc += o;
  }
  const uint32_t wtotal = __shfl(inc, 63);

  __shared__ uint32_t s_wtot[4];
  if (lane == 63) s_wtot[wid] = wtotal;
  __syncthreads();
  uint32_t base = 0;
#pragma unroll
  for (int w = 0; w < 4; ++w) if (w < wid) base += s_wtot[w];

  uint32_t pos = base + (inc - (uint32_t)cntl);        // <= 1575 < SEGCAP: no bound check
#pragma unroll
  for (int j = 0; j < K1_ITERS; ++j) {
    if ((mask >> j) & 1u) {
      kl[pos] = make_key(p[j], (uint32_t)(row0 + t + j * K1_TH));
      ++pos;
    }
  }
  if (t == K1_TH - 1)                                  // wid==3, lane==63
    cnts[img * K1_SLICES + slice] = base + wtotal;
}

// ---------------- K2: select + bucket-scatter sort + gather (one block/image) ----------------
__global__ __launch_bounds__(NTH, 1) void select_kernel(const float* __restrict__ x,
                                                        const unsigned long long* __restrict__ keys,
                                                        const uint32_t* __restrict__ cnts,
                                                        float* __restrict__ out,
                                                        float4* __restrict__ boxes) {
  __shared__ uint32_t s_hist[NBUCK];                 // 16 KB (pristine counts)
  __shared__ uint32_t s_pos[NBUCK];                  // 16 KB (scatter cursors)
  __shared__ unsigned long long s_sorted[CAP];       // 16 KB
  __shared__ unsigned long long s_final[TOPK];       // 8 KB
  __shared__ uint32_t s_wsum[16];
  __shared__ uint32_t s_cnt16[K1_SLICES];
  __shared__ int s_cut;

  const int t = threadIdx.x;
  const int b = blockIdx.x;
  const int lane = t & 63;
  const int wid = t >> 6;
  const float* __restrict__ xb = x + (size_t)b * NBOX * NCH;
  const unsigned long long* __restrict__ kb0 = keys + (size_t)b * K1_SLICES * SEGCAP;

  // ---- init + histogram over 16 segments
#pragma unroll
  for (int j = 0; j < NBUCK / NTH; ++j) s_hist[t + j * NTH] = 0u;
  s_final[t] = 0ull;
  if (t < K1_SLICES) {
    uint32_t c = cnts[b * K1_SLICES + t];
    s_cnt16[t] = (c > SEGCAP) ? SEGCAP : c;          // defensive clamp
  }
  if (t == 0) s_cut = 0;
  __syncthreads();
#pragma unroll
  for (int s = 0; s < K1_SLICES; ++s) {
    const int cs_ = (int)s_cnt16[s];
    const unsigned long long* seg = kb0 + (size_t)s * SEGCAP;
    for (int j = t; j < cs_; j += NTH)
      atomicAdd(&s_hist[bucket_of((uint32_t)(seg[j] >> 32))], 1u);
  }
  __syncthreads();

  // ---- fine suffix scan over 4096 buckets (thread t owns quad 4t..4t+3)
  const uint32_t h0 = s_hist[4 * t], h1 = s_hist[4 * t + 1];
  const uint32_t h2 = s_hist[4 * t + 2], h3 = s_hist[4 * t + 3];
  const uint32_t qs = h0 + h1 + h2 + h3;
  uint32_t v = qs;
#pragma unroll
  for (int off = 1; off < 64; off <<= 1) {           // inclusive suffix within wave
    const uint32_t o = __shfl_down(v, off);
    if (lane + off < 64) v += o;
  }
  if (lane == 0) s_wsum[wid] = v;
  __syncthreads();
  uint32_t tail = 0;
#pragma unroll
  for (int w = 0; w < 16; ++w) if (w > wid) tail += s_wsum[w];
  const uint32_t after = (v - qs) + tail;            // sum of buckets after my quad
  const uint32_t e3 = after, e2 = after + h3, e1 = e2 + h2, e0 = e1 + h1;
  s_pos[4 * t] = e0; s_pos[4 * t + 1] = e1;
  s_pos[4 * t + 2] = e2; s_pos[4 * t + 3] = e3;
  int cand = -1;                                     // cutoff vote: wave-reduced max
  if (e3 + h3 >= TOPK) cand = 4 * t + 3;
  else if (e2 + h2 >= TOPK) cand = 4 * t + 2;
  else if (e1 + h1 >= TOPK) cand = 4 * t + 1;
  else if (e0 + h0 >= TOPK) cand = 4 * t;
  int wmax = cand;
#pragma unroll
  for (int off = 32; off > 0; off >>= 1) {
    const int o = __shfl_down(wmax, off);
    if (o > wmax) wmax = o;
  }
  if (lane == 0 && wmax >= 0) atomicMax(&s_cut, wmax);
  __syncthreads();
  const int cut = s_cut;
  int M = (int)(s_pos[cut] + s_hist[cut]);           // # keys in buckets >= cut
  if (M > CAP) M = CAP;
  __syncthreads();                                   // all read M before cursors move

  // ---- scatter keys >= cut into bucket slices
#pragma unroll
  for (int s = 0; s < K1_SLICES; ++s) {
    const int cs_ = (int)s_cnt16[s];
    const unsigned long long* seg = kb0 + (size_t)s * SEGCAP;
    for (int j = t; j < cs_; j += NTH) {
      const unsigned long long key = seg[j];
      const uint32_t bk = bucket_of((uint32_t)(key >> 32));
      if ((int)bk >= cut) {
        const uint32_t pos = atomicAdd(&s_pos[bk], 1u);
        if (pos < CAP) s_sorted[pos] = key;
      }
    }
  }
  __syncthreads();

  // ---- exact in-bucket rank (slices are tiny: ~1-3 keys)
  for (int p = t; p < M; p += NTH) {
    const unsigned long long key = s_sorted[p];
    const uint32_t bk = bucket_of((uint32_t)(key >> 32));
    int end = (int)s_pos[bk]; if (end > M) end = M;
    int start = end - (int)s_hist[bk]; if (start < 0) start = 0;
    int lr = 0;
    for (int q = start; q < end; ++q) lr += (int)(s_sorted[q] > key);
    const int fp = start + lr;
    if (fp < TOPK) s_final[fp] = key;
  }
  __syncthreads();

  // ---- gather rows of top-1024; write unscaled dets + boxes
  const unsigned long long mykey = s_final[t];
  const uint32_t sbits = (uint32_t)(mykey >> 32);
  const int src = (int)(0xFFFFFFFFu - (uint32_t)(mykey & 0xFFFFFFFFull));
  const bool valid = (sbits != 0u);
  const float conf = valid ? __uint_as_float(sbits) : 0.0f;

  float x1 = 0.f, y1 = 0.f, x2 = 0.f, y2 = 0.f;
  float lm0=0.f,lm1=0.f,lm2=0.f,lm3=0.f,lm4=0.f,lm5=0.f,lm6=0.f,lm7=0.f,lm8=0.f,lm9=0.f;
  if (valid) {
    const float4* rp = (const float4*)(xb + (size_t)src * NCH);
    const float4 q0 = rp[0], q1 = rp[1], q2 = rp[2], q3 = rp[3];
    x1 = q0.x - q0.z * 0.5f;
    y1 = q0.y - q0.w * 0.5f;
    x2 = q0.x + q0.z * 0.5f;
    y2 = q0.y + q0.w * 0.5f;
    lm0 = q1.y; lm1 = q1.z; lm2 = q1.w;
    lm3 = q2.x; lm4 = q2.y; lm5 = q2.z; lm6 = q2.w;
    lm7 = q3.x; lm8 = q3.y; lm9 = q3.z;
  }
  boxes[(size_t)b * TOPK + t] = make_float4(x1, y1, x2, y2);
  float4* op = (float4*)(out + ((size_t)b * TOPK + (size_t)t) * NCH);
  op[0] = make_float4(x1, y1, x2, y2);
  op[1] = make_float4(conf, lm0, lm1, lm2);
  op[2] = make_float4(lm3, lm4, lm5, lm6);
  op[3] = make_float4(lm7, lm8, lm9, 0.0f);
}

// ---------------- K2m: suppression bit-matrix, lower triangle (full-GPU) ----------------
// grid = 64 images x 34 blocks; block = 256 thr. Wave w of block bl owns linear word-tile
// q = bl*4+w in [0,136): rt = triangular row, jw = q - tri(rt). Perfect packing, no idle waves.
__global__ __launch_bounds__(256) void mask_kernel(const float4* __restrict__ boxes,
                                                   unsigned long long* __restrict__ masks) {
  const int img = blockIdx.x / MASK_BLKS;
  const int bl = blockIdx.x % MASK_BLKS;
  const int t = threadIdx.x;
  const int lane = t & 63;
  const int wid = t >> 6;
  const int q = bl * 4 + wid;                          // 0..135, wave-uniform

  int rt = 0;                                          // triangular decode (<=16 iters)
  while (q >= (rt + 1) * (rt + 2) / 2) ++rt;
  const int jw = q - rt * (rt + 1) / 2;

  __shared__ float4 s_rbox[4][64];                     // per-wave row-box slab
  __shared__ float s_rarea[4][64];
  {
    const float4 rb = boxes[(size_t)img * TOPK + rt * 64 + lane];
    s_rbox[wid][lane] = rb;
    s_rarea[wid][lane] = fmaxf(rb.z - rb.x, 0.f) * fmaxf(rb.w - rb.y, 0.f);
  }
  __syncthreads();

  const float4 cb = boxes[(size_t)img * TOPK + jw * 64 + lane];  // my column box
  const float ca = fmaxf(cb.z - cb.x, 0.f) * fmaxf(cb.w - cb.y, 0.f);

  unsigned long long myword = 0ull;
  for (int rl = 0; rl < 64; ++rl) {
    const float4 rb = s_rbox[wid][rl];                 // broadcast row box
    const float ra = s_rarea[wid][rl];                 // hoisted row area
    const float iw = fmaxf(fminf(cb.z, rb.z) - fmaxf(cb.x, rb.x), 0.f);
    const float ih = fmaxf(fminf(cb.w, rb.w) - fmaxf(cb.y, rb.y), 0.f);
    const float inter = iw * ih;
    const float den = ((ca + ra) - inter) + 1e-9f;     // area_col + area_row, ref order
    const bool sup = (double)inter > M45 * (double)den;
    unsigned long long bal = __ballot(sup);
    if (jw == rt) bal &= ((1ull << rl) - 1ull);        // only cols < row on the diagonal
    if (lane == rl) myword = bal;
  }
  masks[((size_t)img * 16 + jw) * TOPK + rt * 64 + lane] = myword;
}

// ---------------- K3: greedy closure, victim-sparse chain (one block/image) ----------------
__global__ __launch_bounds__(NTH, 1) void greedy_kernel(const unsigned long long* __restrict__ masks,
                                                        float* __restrict__ out) {
  __shared__ unsigned long long s_alive[16];
  const int t = threadIdx.x;
  const int b = blockIdx.x;
  const int lane = t & 63;
  const int wid = t >> 6;

  // my diagonal-tile word: which earlier in-tile lanes suppress me (lower-masked)
  const unsigned long long diag = masks[((size_t)b * 16 + wid) * TOPK + t];

  bool keep = true;
  unsigned long long acc = 0ull;     // suppressors from earlier (finalized) tiles

  for (int tile = 0; tile < 16; ++tile) {
    // issue the cross-tile mask load before the barrier (independent of s_alive)
    unsigned long long mw = 0ull;
    if (wid > tile) mw = masks[((size_t)b * 16 + tile) * TOPK + t];

    if (wid == tile) {               // wave-uniform diagonal resolution
      if (acc) keep = false;
      // victim-sparse sequential greedy: only lanes with diag != 0 can flip
      unsigned long long vm = __ballot(diag != 0ull);
      while (vm) {
        const int vv = __ffsll((long long)vm) - 1;
        vm &= vm - 1ull;
        const unsigned long long alive = __ballot(keep);
        if (lane == vv && (alive & diag)) keep = false;
      }
      const unsigned long long fin = __ballot(keep);
      if (lane == 0) s_alive[tile] = fin;
    }
    __syncthreads();
    if (wid > tile) acc |= mw & s_alive[tile];
  }

  if (!keep) {
    float4* op = (float4*)(out + ((size_t)b * TOPK + (size_t)t) * NCH);
    const float4 z = make_float4(0.f, 0.f, 0.f, 0.f);
    op[0] = z; op[1] = z; op[2] = z; op[3] = z;
  }
}

extern "C" void kernel_launch(void* const* d_in, const int* in_sizes, int n_in,
                              void* d_out, int out_size, void* d_ws, size_t ws_size,
                              hipStream_t stream) {
  const float* x = (const float*)d_in[0];
  float* out = (float*)d_out;
  uint32_t* cnts = (uint32_t*)d_ws;                                   // 64*16 u32, always written
  unsigned long long* keys = (unsigned long long*)((char*)d_ws + OFF_KEYS);
  float4* boxes = (float4*)((char*)d_ws + OFF_BOXES);
  unsigned long long* masks = (unsigned long long*)((char*)d_ws + OFF_MASKS);

  score_kernel<<<dim3(64 * K1_SLICES), dim3(K1_TH), 0, stream>>>(x, keys, cnts);
  select_kernel<<<dim3(64), dim3(NTH), 0, stream>>>(x, keys, cnts, out, boxes);
  mask_kernel<<<dim3(64 * MASK_BLKS), dim3(256), 0, stream>>>(boxes, masks);
  greedy_kernel<<<dim3(64), dim3(NTH), 0, stream>>>(masks, out);
}